// Round 6
// baseline (570.752 us; speedup 1.0000x reference)
//
#include <hip/hip_runtime.h>
#include <hip/hip_bf16.h>

#define N_SEQ 2048
#define DMODEL 1024
#define NHEAD 16
#define HD 64
#define NREL 199   // 2*MAX_REL-1

typedef __bf16 bf16x8 __attribute__((ext_vector_type(8)));
typedef float f32x4 __attribute__((ext_vector_type(4)));

__device__ __forceinline__ float bl(unsigned u) { return __uint_as_float(u << 16); }
__device__ __forceinline__ float bh(unsigned u) { return __uint_as_float(u & 0xffff0000u); }

__device__ __forceinline__ bf16x8 cvt8(float4 a, float4 b) {
    bf16x8 r;
    r[0] = (__bf16)a.x; r[1] = (__bf16)a.y; r[2] = (__bf16)a.z; r[3] = (__bf16)a.w;
    r[4] = (__bf16)b.x; r[5] = (__bf16)b.y; r[6] = (__bf16)b.z; r[7] = (__bf16)b.w;
    return r;
}

// C(fp32 or bf16) = A[M,K](fp32 or bf16, stride lda) @ W[Nc,K](fp32)^T + bias(fp32).
// A_IS_BF16: proj GEMM reads the bf16 ctx workspace. OUT_BF16: qkv GEMM writes
// the bf16 workspace; proj GEMM writes fp32 d_out.
// Block: 256 threads (4 waves). Tile: BM=128, BN=64, BK=32.
template<bool A_IS_BF16, bool OUT_BF16>
__global__ __launch_bounds__(256) void gemm_bt(
    const void* __restrict__ Ap,
    const float* __restrict__ W,
    const float* __restrict__ bias,
    void* __restrict__ Cout,
    int lda, int Nc, int K, int ldc)
{
    __shared__ __bf16 a_s[128][40];  // +8 pad breaks pow-2 bank stride
    __shared__ __bf16 b_s[64][40];

    const int tid  = threadIdx.x;
    const int wid  = tid >> 6;
    const int lane = tid & 63;
    const int quad = lane >> 4;
    const int l15  = lane & 15;
    const int bm   = blockIdx.y * 128;
    const int bn   = blockIdx.x * 64;
    const int srow = tid >> 2;        // 0..63
    const int scol = (tid & 3) * 8;   // 0,8,16,24

    f32x4 acc[2][4] = {};

    for (int k0 = 0; k0 < K; k0 += 32) {
        bf16x8 a0, a1;
        if (A_IS_BF16) {
            const __bf16* A = (const __bf16*)Ap;
            a0 = *reinterpret_cast<const bf16x8*>(A + (size_t)(bm + srow) * lda + k0 + scol);
            a1 = *reinterpret_cast<const bf16x8*>(A + (size_t)(bm + 64 + srow) * lda + k0 + scol);
        } else {
            const float* A = (const float*)Ap;
            const float4* p0 = reinterpret_cast<const float4*>(A + (size_t)(bm + srow) * lda + k0 + scol);
            const float4* p1 = reinterpret_cast<const float4*>(A + (size_t)(bm + 64 + srow) * lda + k0 + scol);
            a0 = cvt8(p0[0], p0[1]);
            a1 = cvt8(p1[0], p1[1]);
        }
        const float4* pw = reinterpret_cast<const float4*>(W + (size_t)(bn + srow) * K + k0 + scol);
        bf16x8 w0 = cvt8(pw[0], pw[1]);

        *reinterpret_cast<bf16x8*>(&a_s[srow][scol])      = a0;
        *reinterpret_cast<bf16x8*>(&a_s[64 + srow][scol]) = a1;
        *reinterpret_cast<bf16x8*>(&b_s[srow][scol])      = w0;
        __syncthreads();

        // A-frag: A[m=l15][k=quad*8+j]; B-frag holds B[k=quad*8+j][n=l15] = W[n][k]
        bf16x8 af0 = *reinterpret_cast<const bf16x8*>(&a_s[wid * 32 + l15][quad * 8]);
        bf16x8 af1 = *reinterpret_cast<const bf16x8*>(&a_s[wid * 32 + 16 + l15][quad * 8]);
        #pragma unroll
        for (int t = 0; t < 4; t++) {
            bf16x8 bf = *reinterpret_cast<const bf16x8*>(&b_s[t * 16 + l15][quad * 8]);
            acc[0][t] = __builtin_amdgcn_mfma_f32_16x16x32_bf16(af0, bf, acc[0][t], 0, 0, 0);
            acc[1][t] = __builtin_amdgcn_mfma_f32_16x16x32_bf16(af1, bf, acc[1][t], 0, 0, 0);
        }
        __syncthreads();
    }

    // C/D layout: col = lane&15, row = quad*4 + reg
    #pragma unroll
    for (int t = 0; t < 4; t++) {
        int col = bn + t * 16 + l15;
        float bv = bias[col];
        #pragma unroll
        for (int mi = 0; mi < 2; mi++) {
            #pragma unroll
            for (int ri = 0; ri < 4; ri++) {
                int row = bm + wid * 32 + mi * 16 + quad * 4 + ri;
                float v = acc[mi][t][ri] + bv;
                if (OUT_BF16)
                    reinterpret_cast<__bf16*>(Cout)[(size_t)row * ldc + col] = (__bf16)v;
                else
                    reinterpret_cast<float*>(Cout)[(size_t)row * ldc + col] = v;
            }
        }
    }
}

// Band attention: scores[h,r,j] = 0.125*q_r.k_j + q_r.rel[h, 99+j-r], |j-r|<=99.
// qkv bf16 [N][3072] workspace (q|k|v chunks, head h at h*64). rel_emb fp32.
// One wave per (h,r); ctx written in place over q[r][h*64..+64) — race-free
// (only this wave ever reads/writes those 64 cells).
__global__ __launch_bounds__(256) void attn_band(
    __hip_bfloat16* __restrict__ qkv,
    const float* __restrict__ rel_emb)
{
    const int wid  = threadIdx.x >> 6;
    const int lane = threadIdx.x & 63;
    const int h    = blockIdx.x >> 9;
    const int rg   = blockIdx.x & 511;
    const int r    = rg * 4 + wid;

    __shared__ float p_s[4][256];

    const uint4* qv = reinterpret_cast<const uint4*>(qkv + (size_t)r * 3072 + h * HD);
    float qf[64];
    #pragma unroll
    for (int i = 0; i < 8; i++) {
        uint4 u = qv[i];
        qf[8*i+0] = bl(u.x); qf[8*i+1] = bh(u.x);
        qf[8*i+2] = bl(u.y); qf[8*i+3] = bh(u.y);
        qf[8*i+4] = bl(u.z); qf[8*i+5] = bh(u.z);
        qf[8*i+6] = bl(u.w); qf[8*i+7] = bh(u.w);
    }

    const int lo  = (r - 99 > 0) ? (r - 99) : 0;
    const int hi  = (r + 99 < N_SEQ - 1) ? (r + 99) : (N_SEQ - 1);
    const int len = hi - lo + 1;   // 100..199

    float sc[4];
    float mx = -3.0e38f;
    #pragma unroll
    for (int jb = 0; jb < 4; jb++) {
        const int jj = jb * 64 + lane;
        float sv = -3.0e38f;
        if (jj < len) {
            const int j = lo + jj;
            const uint4* kv = reinterpret_cast<const uint4*>(qkv + (size_t)j * 3072 + 1024 + h * HD);
            float a = 0.f;
            #pragma unroll
            for (int i = 0; i < 8; i++) {
                uint4 u = kv[i];
                a += qf[8*i+0] * bl(u.x) + qf[8*i+1] * bh(u.x)
                   + qf[8*i+2] * bl(u.y) + qf[8*i+3] * bh(u.y)
                   + qf[8*i+4] * bl(u.z) + qf[8*i+5] * bh(u.z)
                   + qf[8*i+6] * bl(u.w) + qf[8*i+7] * bh(u.w);
            }
            const int e = j - r + 99;   // 0..198
            const float4* ev = reinterpret_cast<const float4*>(rel_emb + ((size_t)h * NREL + e) * HD);
            float rr = 0.f;
            #pragma unroll
            for (int i = 0; i < 16; i++) {
                float4 u = ev[i];
                rr += qf[4*i+0] * u.x + qf[4*i+1] * u.y
                    + qf[4*i+2] * u.z + qf[4*i+3] * u.w;
            }
            sv = a * 0.125f + rr;
        }
        sc[jb] = sv;
        mx = fmaxf(mx, sv);
    }
    #pragma unroll
    for (int off = 32; off >= 1; off >>= 1) mx = fmaxf(mx, __shfl_xor(mx, off, 64));

    float sum = 0.f;
    #pragma unroll
    for (int jb = 0; jb < 4; jb++) {
        float p = __expf(sc[jb] - mx);   // masked lanes: exp(-huge) = 0
        p_s[wid][jb * 64 + lane] = p;
        sum += p;
    }
    #pragma unroll
    for (int off = 32; off >= 1; off >>= 1) sum += __shfl_xor(sum, off, 64);
    const float inv = 1.0f / sum;
    __syncthreads();

    float o = 0.f;
    const __hip_bfloat16* vcol = qkv + 2048 + h * HD + lane;
    for (int jj = 0; jj < len; jj++)
        o += p_s[wid][jj] * __bfloat162float(vcol[(size_t)(lo + jj) * 3072]);

    qkv[(size_t)r * 3072 + h * HD + lane] = __float2bfloat16(o * inv);
}

extern "C" void kernel_launch(void* const* d_in, const int* in_sizes, int n_in,
                              void* d_out, int out_size, void* d_ws, size_t ws_size,
                              hipStream_t stream)
{
    (void)out_size; (void)ws_size; (void)n_in;

    // Bind inputs by element count (order-agnostic; all six are distinct).
    const float *x = nullptr, *qkv_w = nullptr, *qkv_b = nullptr;
    const float *proj_w = nullptr, *proj_b = nullptr, *rel = nullptr;
    for (int i = 0; i < 6; i++) {
        switch (in_sizes[i]) {
            case 2097152: x      = (const float*)d_in[i]; break;  // [1,2048,1024]
            case 3145728: qkv_w  = (const float*)d_in[i]; break;  // [3072,1024]
            case 3072:    qkv_b  = (const float*)d_in[i]; break;  // [3072]
            case 1048576: proj_w = (const float*)d_in[i]; break;  // [1024,1024]
            case 1024:    proj_b = (const float*)d_in[i]; break;  // [1024]
            case 203776:  rel    = (const float*)d_in[i]; break;  // [16,199,64]
            default: break;
        }
    }

    __hip_bfloat16* qkv = (__hip_bfloat16*)d_ws;   // [2048][3072] bf16 = 12.58 MB
    float* out = (float*)d_out;                    // [2048][1024] fp32

    // qkv = x @ qkv_w^T + qkv_b  (bf16 workspace out, row stride 3072)
    gemm_bt<false, true><<<dim3(3072 / 64, N_SEQ / 128), 256, 0, stream>>>(
        (const void*)x, qkv_w, qkv_b, (void*)qkv, DMODEL, 3072, DMODEL, 3072);
    // band attention; ctx written in place over the q chunk of qkv
    attn_band<<<dim3(NHEAD * N_SEQ / 4), 256, 0, stream>>>(qkv, rel);
    // out = ctx @ proj_w^T + proj_b  (fp32 out, A = q chunk of qkv, stride 3072)
    gemm_bt<true, false><<<dim3(DMODEL / 64, N_SEQ / 128), 256, 0, stream>>>(
        (const void*)qkv, proj_w, proj_b, (void*)out, 3072, DMODEL, DMODEL, DMODEL);
}

// Round 7
// 155.598 us; speedup vs baseline: 3.6681x; 3.6681x over previous
//
#include <hip/hip_runtime.h>
#include <hip/hip_bf16.h>

#define N_SEQ 2048
#define DMODEL 1024
#define NHEAD 16
#define HD 64
#define NREL 199   // 2*MAX_REL-1

typedef __bf16 bf16x8 __attribute__((ext_vector_type(8)));
typedef float f32x4 __attribute__((ext_vector_type(4)));

__device__ __forceinline__ bf16x8 cvt8(float4 a, float4 b) {
    bf16x8 r;
    r[0] = (__bf16)a.x; r[1] = (__bf16)a.y; r[2] = (__bf16)a.z; r[3] = (__bf16)a.w;
    r[4] = (__bf16)b.x; r[5] = (__bf16)b.y; r[6] = (__bf16)b.z; r[7] = (__bf16)b.w;
    return r;
}

#define MFMA16(A, B, C) __builtin_amdgcn_mfma_f32_16x16x32_bf16(A, B, C, 0, 0, 0)

// ---------------------------------------------------------------------------
// GEMM (unchanged from round 5): C = A @ W^T + bias, MFMA 16x16x32 bf16.
template<bool A_IS_BF16, bool OUT_BF16>
__global__ __launch_bounds__(256) void gemm_bt(
    const void* __restrict__ Ap,
    const float* __restrict__ W,
    const float* __restrict__ bias,
    void* __restrict__ Cout,
    int lda, int Nc, int K, int ldc)
{
    __shared__ __bf16 a_s[128][40];
    __shared__ __bf16 b_s[64][40];

    const int tid  = threadIdx.x;
    const int wid  = tid >> 6;
    const int lane = tid & 63;
    const int quad = lane >> 4;
    const int l15  = lane & 15;
    const int bm   = blockIdx.y * 128;
    const int bn   = blockIdx.x * 64;
    const int srow = tid >> 2;
    const int scol = (tid & 3) * 8;

    f32x4 acc[2][4] = {};

    for (int k0 = 0; k0 < K; k0 += 32) {
        bf16x8 a0, a1;
        if (A_IS_BF16) {
            const __bf16* A = (const __bf16*)Ap;
            a0 = *reinterpret_cast<const bf16x8*>(A + (size_t)(bm + srow) * lda + k0 + scol);
            a1 = *reinterpret_cast<const bf16x8*>(A + (size_t)(bm + 64 + srow) * lda + k0 + scol);
        } else {
            const float* A = (const float*)Ap;
            const float4* p0 = reinterpret_cast<const float4*>(A + (size_t)(bm + srow) * lda + k0 + scol);
            const float4* p1 = reinterpret_cast<const float4*>(A + (size_t)(bm + 64 + srow) * lda + k0 + scol);
            a0 = cvt8(p0[0], p0[1]);
            a1 = cvt8(p1[0], p1[1]);
        }
        const float4* pw = reinterpret_cast<const float4*>(W + (size_t)(bn + srow) * K + k0 + scol);
        bf16x8 w0 = cvt8(pw[0], pw[1]);

        *reinterpret_cast<bf16x8*>(&a_s[srow][scol])      = a0;
        *reinterpret_cast<bf16x8*>(&a_s[64 + srow][scol]) = a1;
        *reinterpret_cast<bf16x8*>(&b_s[srow][scol])      = w0;
        __syncthreads();

        bf16x8 af0 = *reinterpret_cast<const bf16x8*>(&a_s[wid * 32 + l15][quad * 8]);
        bf16x8 af1 = *reinterpret_cast<const bf16x8*>(&a_s[wid * 32 + 16 + l15][quad * 8]);
        #pragma unroll
        for (int t = 0; t < 4; t++) {
            bf16x8 bf = *reinterpret_cast<const bf16x8*>(&b_s[t * 16 + l15][quad * 8]);
            acc[0][t] = MFMA16(af0, bf, acc[0][t]);
            acc[1][t] = MFMA16(af1, bf, acc[1][t]);
        }
        __syncthreads();
    }

    #pragma unroll
    for (int t = 0; t < 4; t++) {
        int col = bn + t * 16 + l15;
        float bv = bias[col];
        #pragma unroll
        for (int mi = 0; mi < 2; mi++) {
            #pragma unroll
            for (int ri = 0; ri < 4; ri++) {
                int row = bm + wid * 32 + mi * 16 + quad * 4 + ri;
                float v = acc[mi][t][ri] + bv;
                if (OUT_BF16)
                    reinterpret_cast<__bf16*>(Cout)[(size_t)row * ldc + col] = (__bf16)v;
                else
                    reinterpret_cast<float*>(Cout)[(size_t)row * ldc + col] = v;
            }
        }
    }
}

// ---------------------------------------------------------------------------
// MFMA flash-band attention.
// Block = (head h, 64-row q-tile). scores[r,j] = 0.125*(Q K^T)[r,j] + P[r, j-r+99]
// where P = Q_tile @ rel_h^T ([64 x 199], computed in-kernel via MFMA).
// Band |j-r|<=99 -> key window [q0-99, q0+162], <=5 key tiles of 64.
// Online softmax; ctx written in place over the q chunk (race-free as before).
__global__ __launch_bounds__(256) void attn_band_mfma(
    __hip_bfloat16* __restrict__ qkv,   // bf16 [2048][3072]
    const float* __restrict__ rel_emb)  // fp32 [16][199][64]
{
    // LDS overlay, 64768 B total:
    //  q_s  [64][72]  bf16  (9216)
    //  P_s  [64][200] bf16  (25600)   scalar access only
    //  phase1: rel_s [208][72] bf16 (29952)
    //  phase2 (overlays rel_s): k_s[64][72] | v_s[64][72] (V^T) | p_s[64][72]
    __shared__ __align__(16) char smem[64768];
    __bf16 (*q_s)[72]   = (__bf16(*)[72])smem;
    __bf16 (*P_s)[200]  = (__bf16(*)[200])(smem + 9216);
    char* ph            = smem + 9216 + 25600;
    __bf16 (*rel_s)[72] = (__bf16(*)[72])ph;
    __bf16 (*k_s)[72]   = (__bf16(*)[72])ph;
    __bf16 (*v_s)[72]   = (__bf16(*)[72])(ph + 9216);
    __bf16 (*p_s)[72]   = (__bf16(*)[72])(ph + 18432);

    const int tid  = threadIdx.x;
    const int wid  = tid >> 6;
    const int lane = tid & 63;
    const int quad = lane >> 4;
    const int l15  = lane & 15;
    const int h    = blockIdx.x >> 5;
    const int q0   = (blockIdx.x & 31) * 64;
    const int srow = tid >> 2;          // 0..63
    const int sq   = (tid & 3) * 16;    // 0,16,32,48

    const int j_lo   = (q0 - 99 > 0) ? (q0 - 99) : 0;
    const int j_hi   = (q0 + 162 < N_SEQ - 1) ? (q0 + 162) : (N_SEQ - 1);
    const int ntiles = (j_hi - j_lo + 64) >> 6;   // 3..5

    // ---- stage Q tile (coalesced 32 B/thread) ----
    {
        const __hip_bfloat16* src = qkv + (size_t)(q0 + srow) * 3072 + h * HD + sq;
        uint4 u0 = ((const uint4*)src)[0];
        uint4 u1 = ((const uint4*)src)[1];
        *(uint4*)&q_s[srow][sq]     = u0;
        *(uint4*)&q_s[srow][sq + 8] = u1;
    }
    // ---- stage rel_h fp32 -> bf16 ----
    for (int idx = tid; idx < NREL * 4; idx += 256) {
        int er = idx >> 2, ec = (idx & 3) * 16;
        const float4* s = (const float4*)(rel_emb + ((size_t)h * NREL + er) * HD + ec);
        float4 f0 = s[0], f1 = s[1], f2 = s[2], f3 = s[3];
        *(bf16x8*)&rel_s[er][ec]     = cvt8(f0, f1);
        *(bf16x8*)&rel_s[er][ec + 8] = cvt8(f2, f3);
    }
    __syncthreads();

    // ---- P = Q @ rel^T : wave wid owns rows wid*16..+15 ----
    {
        f32x4 pacc[13] = {};
        bf16x8 aq0 = *(const bf16x8*)&q_s[wid * 16 + l15][quad * 8];
        bf16x8 aq1 = *(const bf16x8*)&q_s[wid * 16 + l15][quad * 8 + 32];
        #pragma unroll
        for (int t = 0; t < 13; t++) {
            bf16x8 b0 = *(const bf16x8*)&rel_s[t * 16 + l15][quad * 8];
            bf16x8 b1 = *(const bf16x8*)&rel_s[t * 16 + l15][quad * 8 + 32];
            pacc[t] = MFMA16(aq0, b0, pacc[t]);
            pacc[t] = MFMA16(aq1, b1, pacc[t]);
        }
        #pragma unroll
        for (int t = 0; t < 13; t++)
            #pragma unroll
            for (int ri = 0; ri < 4; ri++) {
                int col = t * 16 + l15;
                if (col < NREL)
                    P_s[wid * 16 + quad * 4 + ri][col] = (__bf16)pacc[t][ri];
            }
    }

    // ---- flash loop over key tiles ----
    float m_i[4], l_i[4], alpha[4];
    f32x4 O[4] = {};
    #pragma unroll
    for (int ri = 0; ri < 4; ri++) { m_i[ri] = -3.0e38f; l_i[ri] = 0.f; }

    for (int t = 0; t < ntiles; t++) {
        __syncthreads();   // previous iter (and phase-1 rel reads) done before overwrite
        const int j0 = j_lo + t * 64;
        {   // stage K tile + V^T tile (clamped row; OOB cols masked later)
            int jr = j0 + srow; if (jr > N_SEQ - 1) jr = N_SEQ - 1;
            const __hip_bfloat16* ks = qkv + (size_t)jr * 3072 + 1024 + h * HD + sq;
            uint4 k0 = ((const uint4*)ks)[0], k1 = ((const uint4*)ks)[1];
            *(uint4*)&k_s[srow][sq]     = k0;
            *(uint4*)&k_s[srow][sq + 8] = k1;
            const __hip_bfloat16* vsp = qkv + (size_t)jr * 3072 + 2048 + h * HD + sq;
            uint4 v0 = ((const uint4*)vsp)[0], v1 = ((const uint4*)vsp)[1];
            __bf16 vtmp[16];
            *(uint4*)&vtmp[0] = v0; *(uint4*)&vtmp[8] = v1;
            #pragma unroll
            for (int i = 0; i < 16; i++) v_s[sq + i][srow] = vtmp[i];
        }
        __syncthreads();

        // S = Q K^T for this wave's 16 rows
        f32x4 S[4] = {};
        bf16x8 aq0 = *(const bf16x8*)&q_s[wid * 16 + l15][quad * 8];
        bf16x8 aq1 = *(const bf16x8*)&q_s[wid * 16 + l15][quad * 8 + 32];
        #pragma unroll
        for (int nt = 0; nt < 4; nt++) {
            bf16x8 b0 = *(const bf16x8*)&k_s[nt * 16 + l15][quad * 8];
            bf16x8 b1 = *(const bf16x8*)&k_s[nt * 16 + l15][quad * 8 + 32];
            S[nt] = MFMA16(aq0, b0, S[nt]);
            S[nt] = MFMA16(aq1, b1, S[nt]);
        }

        // scores = 0.125*S + P[r, e], band mask; C layout row=quad*4+ri, col=nt*16+l15
        float sc[4][4];
        float tmax[4] = {-3.0e38f, -3.0e38f, -3.0e38f, -3.0e38f};
        #pragma unroll
        for (int nt = 0; nt < 4; nt++)
            #pragma unroll
            for (int ri = 0; ri < 4; ri++) {
                int r_loc = wid * 16 + quad * 4 + ri;
                int jg = j0 + nt * 16 + l15;
                int e  = jg - (q0 + r_loc) + 99;
                float v = -3.0e38f;
                if (e >= 0 && e < NREL && jg < N_SEQ)
                    v = S[nt][ri] * 0.125f + (float)P_s[r_loc][e];
                sc[nt][ri] = v;
                tmax[ri] = fmaxf(tmax[ri], v);
            }
        #pragma unroll
        for (int ri = 0; ri < 4; ri++)
            #pragma unroll
            for (int mk = 1; mk < 16; mk <<= 1)
                tmax[ri] = fmaxf(tmax[ri], __shfl_xor(tmax[ri], mk, 64));

        #pragma unroll
        for (int ri = 0; ri < 4; ri++) {
            float mn = fmaxf(m_i[ri], tmax[ri]);
            alpha[ri] = (m_i[ri] > -1.0e30f) ? __expf(m_i[ri] - mn) : 0.f;
            m_i[ri] = mn;
        }

        float tsum[4] = {0.f, 0.f, 0.f, 0.f};
        #pragma unroll
        for (int nt = 0; nt < 4; nt++)
            #pragma unroll
            for (int ri = 0; ri < 4; ri++) {
                float p = (sc[nt][ri] > -1.0e30f) ? __expf(sc[nt][ri] - m_i[ri]) : 0.f;
                __bf16 pb = (__bf16)p;
                p_s[wid * 16 + quad * 4 + ri][nt * 16 + l15] = pb;
                tsum[ri] += (float)pb;
            }
        #pragma unroll
        for (int ri = 0; ri < 4; ri++) {
            #pragma unroll
            for (int mk = 1; mk < 16; mk <<= 1)
                tsum[ri] += __shfl_xor(tsum[ri], mk, 64);
            l_i[ri] = l_i[ri] * alpha[ri] + tsum[ri];
        }
        #pragma unroll
        for (int nt = 0; nt < 4; nt++)
            #pragma unroll
            for (int ri = 0; ri < 4; ri++) O[nt][ri] *= alpha[ri];

        // O += probs @ V  (A = p_s own rows, B = v_s holds V^T)
        bf16x8 ap0 = *(const bf16x8*)&p_s[wid * 16 + l15][quad * 8];
        bf16x8 ap1 = *(const bf16x8*)&p_s[wid * 16 + l15][quad * 8 + 32];
        #pragma unroll
        for (int nt = 0; nt < 4; nt++) {
            bf16x8 b0 = *(const bf16x8*)&v_s[nt * 16 + l15][quad * 8];
            bf16x8 b1 = *(const bf16x8*)&v_s[nt * 16 + l15][quad * 8 + 32];
            O[nt] = MFMA16(ap0, b0, O[nt]);
            O[nt] = MFMA16(ap1, b1, O[nt]);
        }
    }

    // ---- epilogue: ctx = O / l, in place over q chunk ----
    #pragma unroll
    for (int nt = 0; nt < 4; nt++)
        #pragma unroll
        for (int ri = 0; ri < 4; ri++) {
            int r = q0 + wid * 16 + quad * 4 + ri;
            qkv[(size_t)r * 3072 + h * HD + nt * 16 + l15] =
                __float2bfloat16(O[nt][ri] / l_i[ri]);
        }
}

extern "C" void kernel_launch(void* const* d_in, const int* in_sizes, int n_in,
                              void* d_out, int out_size, void* d_ws, size_t ws_size,
                              hipStream_t stream)
{
    (void)out_size; (void)ws_size; (void)n_in;

    const float *x = nullptr, *qkv_w = nullptr, *qkv_b = nullptr;
    const float *proj_w = nullptr, *proj_b = nullptr, *rel = nullptr;
    for (int i = 0; i < 6; i++) {
        switch (in_sizes[i]) {
            case 2097152: x      = (const float*)d_in[i]; break;
            case 3145728: qkv_w  = (const float*)d_in[i]; break;
            case 3072:    qkv_b  = (const float*)d_in[i]; break;
            case 1048576: proj_w = (const float*)d_in[i]; break;
            case 1024:    proj_b = (const float*)d_in[i]; break;
            case 203776:  rel    = (const float*)d_in[i]; break;
            default: break;
        }
    }

    __hip_bfloat16* qkv = (__hip_bfloat16*)d_ws;   // [2048][3072] bf16
    float* out = (float*)d_out;                    // [2048][1024] fp32

    gemm_bt<false, true><<<dim3(3072 / 64, N_SEQ / 128), 256, 0, stream>>>(
        (const void*)x, qkv_w, qkv_b, (void*)qkv, DMODEL, 3072, DMODEL, 3072);
    attn_band_mfma<<<dim3(NHEAD * (N_SEQ / 64)), 256, 0, stream>>>(qkv, rel);
    gemm_bt<true, false><<<dim3(DMODEL / 64, N_SEQ / 128), 256, 0, stream>>>(
        (const void*)qkv, proj_w, proj_b, (void*)out, 3072, DMODEL, DMODEL, DMODEL);
}